// Round 5
// baseline (872.256 us; speedup 1.0000x reference)
//
#include <hip/hip_runtime.h>
#include <hip/hip_bf16.h>
#include <math.h>

#define HWD 262144   // 64*64*64

typedef __attribute__((ext_vector_type(8))) short bf16x8;   // 8 bf16 (4 VGPRs)
typedef __attribute__((ext_vector_type(16))) float f32x16;  // MFMA 32x32 accumulator

// ---------------- prep: weights -> bf16 GEMM layout A[ks 72][oc 128][kk 16]; w_map -> Wb bf16 ----
// K order: k = ((g*3+r)*3+s)*64 + z,  ks=k>>4, kk=k&15.
__global__ void k_prep(const float* __restrict__ w_t, const float* __restrict__ w_c,
                       const float* __restrict__ w_map,
                       __hip_bfloat16* __restrict__ A_t, __hip_bfloat16* __restrict__ A_c,
                       __hip_bfloat16* __restrict__ Wb) {
    int i = blockIdx.x * 256 + threadIdx.x;
    if (i < 147456) {
        int kk = i & 15, oc = (i >> 4) & 127, ks = i >> 11;
        int z4 = ks & 3, kq = ks >> 2;          // kq = (g*3+r)*3+s in [0,18)
        int g = kq / 9, tap = kq - 9 * g;       // tap = r*3+s
        int z = z4 * 16 + kk;
        // w_t (128,2,64,3,3): ((o*2+g)*64+kh)*9 + tap,  z=kh
        A_t[i] = __float2bfloat16(w_t[((oc * 2 + g) * 64 + z) * 9 + tap]);
        // w_c (128,2,3,3,64): ((o*2+g)*9+tap)*64 + kd,  z=kd
        A_c[i] = __float2bfloat16(w_c[((oc * 2 + g) * 9 + tap) * 64 + z]);
    }
    if (i < 8192) {
        Wb[i] = __float2bfloat16(w_map[i]);   // w_map is (C,2C) row-major = [c][k]
    }
}

__device__ inline void pack_row_bf16(__hip_bfloat16* dst, const float* src) {
    unsigned short u[16];
#pragma unroll
    for (int j = 0; j < 16; ++j) {
        __hip_bfloat16 h = __float2bfloat16(src[j]);
        u[j] = *reinterpret_cast<unsigned short*>(&h);
    }
    uint4* q = reinterpret_cast<uint4*>(dst);
    q[0] = *reinterpret_cast<const uint4*>(&u[0]);
    q[1] = *reinterpret_cast<const uint4*>(&u[8]);
}

// ---------------- transpose x (B,N,C) -> Xc bf16, z4-plane layout [cg][z4][h*w][16] ------------
// X'[cg][z4][hw][j] = x-grid[cg][h][w][z4*16+j]. Conv reads 32B-contiguous (z4,16kk) chunks at
// consecutive (p,q): staging becomes a fully-coalesced 4KB load instead of 32B-per-128B-line.
__global__ void k_trans_c(const float* __restrict__ x, __hip_bfloat16* __restrict__ Xc) {
    __shared__ float tile[64][65];
    int b = blockIdx.y;
    long n0 = (long)blockIdx.x * 64;
    int t = threadIdx.x;
    const float4* xp4 = (const float4*)(x + ((long)b * HWD + n0) * 64);
#pragma unroll
    for (int j = 0; j < 4; ++j) {
        int f4i = j * 256 + t;
        float4 v = xp4[f4i];
        int row = f4i >> 4;
        int c4 = (f4i & 15) * 4;
        tile[c4 + 0][row] = v.x;
        tile[c4 + 1][row] = v.y;
        tile[c4 + 2][row] = v.z;
        tile[c4 + 3][row] = v.w;
    }
    __syncthreads();
    int c = t >> 2, sub = t & 3;     // sub = z4 plane
    pack_row_bf16(Xc + (long)(b * 64 + c) * HWD + sub * 65536 + (long)blockIdx.x * 16,
                  &tile[c][sub * 16]);
}

// ---------------- transpose x -> Xt bf16, z4-plane layout [cg][z4][w*d][16] (z = h) ------------
__global__ void k_trans_t(const float* __restrict__ x, __hip_bfloat16* __restrict__ Xt) {
    __shared__ float tile[64][65];   // [c][h]
    int b = blockIdx.y;
    int wd = blockIdx.x;             // w*64+d
    int t = threadIdx.x;
#pragma unroll
    for (int j = 0; j < 4; ++j) {
        int f4i = j * 256 + t;       // 64 h x 16 c-quads
        int h = f4i >> 4;
        int c4 = (f4i & 15) * 4;
        float4 v = *(const float4*)(x + ((long)b * HWD + (long)h * 4096 + wd) * 64 + c4);
        tile[c4 + 0][h] = v.x;
        tile[c4 + 1][h] = v.y;
        tile[c4 + 2][h] = v.z;
        tile[c4 + 3][h] = v.w;
    }
    __syncthreads();
    int c = t >> 2, sub = t & 3;     // sub = z4 plane (h-chunk)
    pack_row_bf16(Xt + (long)(b * 64 + c) * HWD + sub * 65536 + (long)wd * 16,
                  &tile[c][sub * 16]);
}

// ---------------- unified MFMA conv: per (b,ch) GEMM C[128][4096] = A[128][1152] * B ----------
// v2 pipeline: A-frags direct from global (4KB/ks panel, L1/L2-resident); B double-buffered
// in LDS with ONE barrier per K-step and next-step B prefetched into regs before the MFMAs
// (load latency overlaps compute instead of sitting inside a vmcnt-drain barrier pair).
// X is z4-plane layout: B-staging = one coalesced 4KB contiguous load per K-step.
__global__ __launch_bounds__(256, 4) void k_conv_mfma(
        const __hip_bfloat16* __restrict__ X, const __hip_bfloat16* __restrict__ Aglob,
        const float* __restrict__ bias, float* __restrict__ Out) {
    int L = blockIdx.x;                       // 2048 = 64 grp * 32 pt
    int grp = (L & 7) * 8 + ((L >> 3) >> 5);  // XCD r handles grps [r*8, r*8+8)
    int pt = (L >> 3) & 31;
    int b = grp >> 5, ch = grp & 31;
    int p0 = pt * 2;
    const __hip_bfloat16* Xg = X + ((long)(b * 64 + 2 * ch)) * HWD;
    int t = threadIdx.x;
    int lane = t & 63, wv = t >> 6;

    __shared__ __align__(16) short Bsm[2 * 128 * 24];   // 2 bufs, rows 16 data + 8 pad = 48B

    f32x16 acc00 = {0}, acc01 = {0}, acc10 = {0}, acc11 = {0};

    int srow = t >> 1, shalf = t & 1;     // staging: row 0..127, 16B half
    int pr = srow >> 6, q = srow & 63;    // B-row -> (p-row, q)
    int O0 = (wv >> 1) * 64;              // wave oc base
    int N0 = (wv & 1) * 64;               // wave n base
    int lrow = lane & 31, lq = lane >> 5;
    const short* Ag = (const short*)Aglob;

    auto loadB = [&](int ks) -> uint4 {
        int z4 = ks & 3, kq = ks >> 2;
        int g = kq / 9, tap = kq - 9 * g;
        int r = tap / 3, s = tap - 3 * r;
        int pp = p0 + pr + r - 1, qq = q + s - 1;
        uint4 bv = {0u, 0u, 0u, 0u};
        if (pp >= 0 && pp < 64 && qq >= 0 && qq < 64)
            bv = *(const uint4*)(Xg + (long)g * HWD + z4 * 65536 + ((pp << 6) + qq) * 16 + shalf * 8);
        return bv;
    };

    // prologue: stage ks=0 into buf 0
    {
        uint4 b0v = loadB(0);
        *(uint4*)(Bsm + srow * 24 + shalf * 8) = b0v;
    }
    __syncthreads();

    int buf = 0;
    for (int ks = 0; ks < 72; ++ks) {
        uint4 bnext;
        if (ks < 71) bnext = loadB(ks + 1);            // issue early: overlaps MFMAs below
        const short* Bc = Bsm + buf * 3072;
        bf16x8 a0 = *(const bf16x8*)(Ag + ks * 2048 + (O0 + lrow) * 16 + lq * 8);
        bf16x8 a1 = *(const bf16x8*)(Ag + ks * 2048 + (O0 + 32 + lrow) * 16 + lq * 8);
        bf16x8 b0 = *(const bf16x8*)(Bc + (N0 + lrow) * 24 + lq * 8);
        bf16x8 b1 = *(const bf16x8*)(Bc + (N0 + 32 + lrow) * 24 + lq * 8);
        acc00 = __builtin_amdgcn_mfma_f32_32x32x16_bf16(a0, b0, acc00, 0, 0, 0);
        acc01 = __builtin_amdgcn_mfma_f32_32x32x16_bf16(a0, b1, acc01, 0, 0, 0);
        acc10 = __builtin_amdgcn_mfma_f32_32x32x16_bf16(a1, b0, acc10, 0, 0, 0);
        acc11 = __builtin_amdgcn_mfma_f32_32x32x16_bf16(a1, b1, acc11, 0, 0, 0);
        if (ks < 71) {
            *(uint4*)(Bsm + (buf ^ 1) * 3072 + srow * 24 + shalf * 8) = bnext;
            __syncthreads();                           // single barrier per K-step
            buf ^= 1;
        }
    }

    // store: C/D layout col=lane&31, row=(reg&3)+8*(reg>>2)+4*(lane>>5)
    long base0 = ((long)(b * 64 + 2 * ch)) * HWD + (long)p0 * 64;
    int n0l = N0 + lrow, n1l = N0 + 32 + lrow;
    long noff0 = (long)(n0l >> 6) * 64 + (n0l & 63);
    long noff1 = (long)(n1l >> 6) * 64 + (n1l & 63);
#pragma unroll
    for (int reg = 0; reg < 16; ++reg) {
        int row = (reg & 3) + 8 * (reg >> 2) + 4 * lq;
        int oc0 = O0 + row, oc1 = O0 + 32 + row;
        long cb0 = base0 + (long)(oc0 >> 6) * HWD + (long)(oc0 & 63) * 4096;
        long cb1 = base0 + (long)(oc1 >> 6) * HWD + (long)(oc1 & 63) * 4096;
        float bs0 = bias[oc0], bs1 = bias[oc1];
        Out[cb0 + noff0] = acc00[reg] + bs0;
        Out[cb0 + noff1] = acc01[reg] + bs0;
        Out[cb1 + noff0] = acc10[reg] + bs1;
        Out[cb1 + noff1] = acc11[reg] + bs1;
    }
}

// ---------------- attn: At[b,c,h,w2,d] = sum_w Cc[b,c,w2,h,w] * T[b,c,w2,w,d] (bf16 out) ----
__global__ void k_attn(const float* __restrict__ Cc, const float* __restrict__ T,
                       __hip_bfloat16* __restrict__ At) {
    __shared__ float As[64][65];
    __shared__ float Bs[64][64];
    int bc = blockIdx.x >> 6, w2 = blockIdx.x & 63;
    const float* Ap = Cc + ((long)bc * 64 + w2) * 4096;
    const float* Bp = T + ((long)bc * 64 + w2) * 4096;
    int t = threadIdx.x;
#pragma unroll
    for (int e0 = 0; e0 < 4096; e0 += 256) {
        int e = e0 + t;
        int r = e >> 6, q = e & 63;
        As[r][q] = Ap[e];
        Bs[r][q] = Bp[e];
    }
    __syncthreads();
    int h = t >> 2, dg = (t & 3) * 16;
    f32x16 acc = {0};
    for (int k = 0; k < 64; ++k) {
        float a = As[h][k];
#pragma unroll
        for (int i = 0; i < 16; ++i)
            acc[i] = fmaf(a, Bs[k][dg + i], acc[i]);
    }
    float tmp[16];
#pragma unroll
    for (int i = 0; i < 16; ++i) tmp[i] = acc[i];
    pack_row_bf16(At + (long)bc * HWD + (long)h * 4096 + w2 * 64 + dg, tmp);
}

// ---------------- f: F[b,c,h,w,d] = sum_w2 Cc[b,c,w2,h,w] * T[b,c,w2,w,d] (bf16 out) ----
// block = (bc, 8-wide w-tile), 512 threads; A staged with float4 (32B contiguous),
// B coalesced; Bs rows padded to 68. XCD swizzle keeps one bc on one XCD.
__global__ __launch_bounds__(512, 4) void k_f(const float* __restrict__ Cc,
        const float* __restrict__ T, __hip_bfloat16* __restrict__ F) {
    __shared__ float As[16][64][8];   // [kk][h][w]        32 KB
    __shared__ float Bs[16][8][68];   // [kk][w][d(+pad)]  34 KB
    int L = blockIdx.x;               // 1024 = 128 bc * 8 wt
    int xcd = L & 7, j = L >> 3;      // j 0..127
    int bc = xcd * 16 + (j >> 3), wt = j & 7;
    const float* Ab = Cc + (long)bc * HWD + wt * 8;
    const float* Bb = T + (long)bc * HWD + wt * 8 * 64;
    int t = threadIdx.x;
    int w = t & 7, h = t >> 3;
    f32x16 acc0 = {0}, acc1 = {0}, acc2 = {0}, acc3 = {0};

    for (int w2c = 0; w2c < 4; ++w2c) {
        __syncthreads();
        // A stage: 16 kk x 64 h x 2 half-float4 (32B contiguous per (kk,h))
#pragma unroll
        for (int i = 0; i < 4; ++i) {
            int f = i * 512 + t;                       // 0..2047
            int half = f & 1, hh = (f >> 1) & 63, kk = f >> 7;
            float4 v = *(const float4*)(Ab + (long)(w2c * 16 + kk) * 4096 + hh * 64 + half * 4);
            *(float4*)&As[kk][hh][half * 4] = v;
        }
        // B stage: 16 kk x 8 w x 16 float4 (256B contiguous per (kk,w))
#pragma unroll
        for (int i = 0; i < 4; ++i) {
            int f = i * 512 + t;
            int d4 = f & 15, ww = (f >> 4) & 7, kk = f >> 7;
            float4 v = *(const float4*)(Bb + (long)(w2c * 16 + kk) * 4096 + ww * 64 + d4 * 4);
            *(float4*)&Bs[kk][ww][d4 * 4] = v;
        }
        __syncthreads();
        for (int kk = 0; kk < 16; ++kk) {
            float a = As[kk][h][w];
            const float* br = &Bs[kk][w][0];
#pragma unroll
            for (int i = 0; i < 16; ++i) {
                acc0[i] = fmaf(a, br[i], acc0[i]);
                acc1[i] = fmaf(a, br[16 + i], acc1[i]);
                acc2[i] = fmaf(a, br[32 + i], acc2[i]);
                acc3[i] = fmaf(a, br[48 + i], acc3[i]);
            }
        }
    }
    // store: F[bc][h][wt*8+w][d], 128B per thread (contiguous)
    __hip_bfloat16* Fp = F + (long)bc * HWD + (long)h * 4096 + (wt * 8 + w) * 64;
    float tmp[16];
#pragma unroll
    for (int i = 0; i < 16; ++i) tmp[i] = acc0[i];
    pack_row_bf16(Fp, tmp);
#pragma unroll
    for (int i = 0; i < 16; ++i) tmp[i] = acc1[i];
    pack_row_bf16(Fp + 16, tmp);
#pragma unroll
    for (int i = 0; i < 16; ++i) tmp[i] = acc2[i];
    pack_row_bf16(Fp + 32, tmp);
#pragma unroll
    for (int i = 0; i < 16; ++i) tmp[i] = acc3[i];
    pack_row_bf16(Fp + 48, tmp);
}

// ---------------- map v4 (MFMA): out[n][c] = gelu( sum_k P[n][k] Wb[k][c] + b_map[c] ) ----
// P[n][k<64] = bf16(x[n][k] * F[k][n]),  P[n][k>=64] = At[k-64][n].
__global__ __launch_bounds__(256, 4) void k_map(const float* __restrict__ x,
        const __hip_bfloat16* __restrict__ F, const __hip_bfloat16* __restrict__ At,
        const __hip_bfloat16* __restrict__ Wb, const float* __restrict__ b_map,
        float* __restrict__ out) {
    __shared__ float xs[16][257];             // 16448 B
    __shared__ __hip_bfloat16 fa[16][264];    //  8448 B, F or At chunk
    __shared__ short Pl[256][24];             // 12288 B, 16 k bf16 + 8 pad
    __shared__ short Wt[64][136];             // 17408 B, [c][k 128 + 8 pad]

    int t = threadIdx.x;
    long n0 = (long)blockIdx.x * 256;
    int b = (int)(n0 >> 18);
    long nn0 = n0 & (HWD - 1);
    const float* xblk = x + n0 * 64;
    const __hip_bfloat16* Fb = F + (long)b * 64 * HWD + nn0;
    const __hip_bfloat16* Ab = At + (long)b * 64 * HWD + nn0;

    // load W tile once: Wb[c][k] 64x128 bf16
#pragma unroll
    for (int i = 0; i < 4; ++i) {
        int e = i * 256 + t;                  // uint4 index, 1024 total
        int c = e >> 4, kk = (e & 15) * 8;
        *(uint4*)&Wt[c][kk] = *(const uint4*)((const short*)Wb + c * 128 + kk);
    }

    int lane = t & 63, wv = t >> 6;
    int lrow = lane & 31, lhalf = lane >> 5;
    f32x16 acc00 = {0}, acc01 = {0}, acc10 = {0}, acc11 = {0};

    for (int kc = 0; kc < 8; ++kc) {
        __syncthreads();   // prev chunk's Pl/xs/fa readers done; covers Wt load at kc=0
        if (kc < 4) {
            // stage x chunk: each 64B line fetched by one float4 instruction
#pragma unroll
            for (int i2 = 0; i2 < 4; ++i2) {
                int f = i2 * 256 + t;
                int nr = f >> 2, j4 = (f & 3) * 4;
                float4 v = *(const float4*)(xblk + nr * 64 + kc * 16 + j4);
                xs[j4 + 0][nr] = v.x;
                xs[j4 + 1][nr] = v.y;
                xs[j4 + 2][nr] = v.z;
                xs[j4 + 3][nr] = v.w;
            }
            // stage F chunk: 16 ch x 512B, uint4, fully coalesced
#pragma unroll
            for (int it = 0; it < 2; ++it) {
                int idx = it * 256 + t;
                int row = idx >> 5, seg = idx & 31;
                *(uint4*)&fa[row][seg * 8] =
                    *(const uint4*)(Fb + (long)(kc * 16 + row) * HWD + seg * 8);
            }
        } else {
            // stage At chunk
#pragma unroll
            for (int it = 0; it < 2; ++it) {
                int idx = it * 256 + t;
                int row = idx >> 5, seg = idx & 31;
                *(uint4*)&fa[row][seg * 8] =
                    *(const uint4*)(Ab + (long)((kc - 4) * 16 + row) * HWD + seg * 8);
            }
        }
        __syncthreads();
        // build P row t (16 bf16), write as 2x16B
        unsigned short pv[16];
        if (kc < 4) {
#pragma unroll
            for (int k2 = 0; k2 < 16; ++k2) {
                float p = xs[k2][t] * __bfloat162float(fa[k2][t]);
                __hip_bfloat16 h = __float2bfloat16(p);
                pv[k2] = *reinterpret_cast<unsigned short*>(&h);
            }
        } else {
#pragma unroll
            for (int k2 = 0; k2 < 16; ++k2)
                pv[k2] = *reinterpret_cast<const unsigned short*>(&fa[k2][t]);
        }
        *(uint4*)&Pl[t][0] = *(uint4*)&pv[0];
        *(uint4*)&Pl[t][8] = *(uint4*)&pv[8];
        __syncthreads();
        // MFMA K-step: A = P rows (n), B = Wt rows (c)
        bf16x8 a0 = *(const bf16x8*)&Pl[wv * 64 + lrow][lhalf * 8];
        bf16x8 a1 = *(const bf16x8*)&Pl[wv * 64 + 32 + lrow][lhalf * 8];
        bf16x8 b0 = *(const bf16x8*)&Wt[lrow][kc * 16 + lhalf * 8];
        bf16x8 b1 = *(const bf16x8*)&Wt[32 + lrow][kc * 16 + lhalf * 8];
        acc00 = __builtin_amdgcn_mfma_f32_32x32x16_bf16(a0, b0, acc00, 0, 0, 0);
        acc01 = __builtin_amdgcn_mfma_f32_32x32x16_bf16(a0, b1, acc01, 0, 0, 0);
        acc10 = __builtin_amdgcn_mfma_f32_32x32x16_bf16(a1, b0, acc10, 0, 0, 0);
        acc11 = __builtin_amdgcn_mfma_f32_32x32x16_bf16(a1, b1, acc11, 0, 0, 0);
    }

    // epilogue: bias + exact GELU + store.
    // D layout: col(c) = lane&31, row(n) = (reg&3)+8*(reg>>2)+4*lhalf
    float bs0 = b_map[lrow];
    float bs1 = b_map[32 + lrow];
    const float inv_sqrt2 = 0.70710678118654752440f;
    float* ob = out + (n0 + wv * 64) * 64;
#pragma unroll
    for (int reg = 0; reg < 16; ++reg) {
        int nrow = (reg & 3) + 8 * (reg >> 2) + 4 * lhalf;
        float v00 = acc00[reg] + bs0;
        float v01 = acc01[reg] + bs1;
        float v10 = acc10[reg] + bs0;
        float v11 = acc11[reg] + bs1;
        v00 = 0.5f * v00 * (1.f + erff(v00 * inv_sqrt2));
        v01 = 0.5f * v01 * (1.f + erff(v01 * inv_sqrt2));
        v10 = 0.5f * v10 * (1.f + erff(v10 * inv_sqrt2));
        v11 = 0.5f * v11 * (1.f + erff(v11 * inv_sqrt2));
        ob[(long)nrow * 64 + lrow] = v00;            // lanes 0-31 + 32-63: 2x128B contig
        ob[(long)nrow * 64 + 32 + lrow] = v01;
        ob[(long)(32 + nrow) * 64 + lrow] = v10;
        ob[(long)(32 + nrow) * 64 + 32 + lrow] = v11;
    }
}

extern "C" void kernel_launch(void* const* d_in, const int* in_sizes, int n_in,
                              void* d_out, int out_size, void* d_ws, size_t ws_size,
                              hipStream_t stream) {
    const float* x     = (const float*)d_in[0];
    const float* w_t   = (const float*)d_in[1];
    const float* b_t   = (const float*)d_in[2];
    const float* w_c   = (const float*)d_in[3];
    const float* b_c   = (const float*)d_in[4];
    const float* w_map = (const float*)d_in[5];
    const float* b_map = (const float*)d_in[6];
    float* out = (float*)d_out;
    float* ws = (float*)d_ws;

    // ws layout (float offsets), ~269 MB total:
    //  [0,        16777216)  Xc bf16  (33.5M elem)  -> reused as At bf16 after conv_c
    //  [16777216, 33554432)  Xt bf16                -> reused as F bf16 after conv_t
    //  [33554432, 67108864)  T fp32
    //  [67108864, ...)       A_t bf16 (147456) | A_c bf16 (147456) | Wb bf16 (8192)
    __hip_bfloat16* Xc = (__hip_bfloat16*)ws;
    __hip_bfloat16* Xt = (__hip_bfloat16*)(ws + 16777216L);
    float* T = ws + 33554432L;
    float* Cc = out;                                     // d_out as scratch
    __hip_bfloat16* A_t = (__hip_bfloat16*)(ws + 67108864L);
    __hip_bfloat16* A_c = (__hip_bfloat16*)(ws + 67182592L);
    __hip_bfloat16* Wb = (__hip_bfloat16*)(ws + 67256320L);
    __hip_bfloat16* At_bf = Xc;                          // 67 MB, Xc dead after convs
    __hip_bfloat16* F_bf = Xt;                           // 67 MB, Xt dead after convs

    hipLaunchKernelGGL(k_prep, dim3(576), dim3(256), 0, stream, w_t, w_c, w_map, A_t, A_c, Wb);
    hipLaunchKernelGGL(k_trans_c, dim3(4096, 2), dim3(256), 0, stream, x, Xc);
    hipLaunchKernelGGL(k_trans_t, dim3(4096, 2), dim3(256), 0, stream, x, Xt);
    hipLaunchKernelGGL(k_conv_mfma, dim3(2048), dim3(256), 0, stream, Xt, A_t, b_t, T);
    hipLaunchKernelGGL(k_conv_mfma, dim3(2048), dim3(256), 0, stream, Xc, A_c, b_c, Cc);
    hipLaunchKernelGGL(k_attn, dim3(8192), dim3(256), 0, stream, Cc, T, At_bf);
    hipLaunchKernelGGL(k_f, dim3(1024), dim3(512), 0, stream, Cc, T, F_bf);
    hipLaunchKernelGGL(k_map, dim3(2048), dim3(256), 0, stream, x, F_bf, At_bf, Wb, b_map, out);
}

// Round 6
// 822.122 us; speedup vs baseline: 1.0610x; 1.0610x over previous
//
#include <hip/hip_runtime.h>
#include <hip/hip_bf16.h>
#include <math.h>

#define HWD 262144   // 64*64*64

typedef __attribute__((ext_vector_type(8))) short bf16x8;   // 8 bf16 (4 VGPRs)
typedef __attribute__((ext_vector_type(16))) float f32x16;  // MFMA 32x32 accumulator

__device__ inline unsigned short bfu(float f) {
    __hip_bfloat16 h = __float2bfloat16(f);
    return *reinterpret_cast<unsigned short*>(&h);
}

// ---------------- prep: weights -> bf16 GEMM layout A[ks 72][oc 128][kk 16]; w_map -> Wb bf16 ----
// K order: k = ((g*3+r)*3+s)*64 + z,  ks=k>>4, kk=k&15.
__global__ void k_prep(const float* __restrict__ w_t, const float* __restrict__ w_c,
                       const float* __restrict__ w_map,
                       __hip_bfloat16* __restrict__ A_t, __hip_bfloat16* __restrict__ A_c,
                       __hip_bfloat16* __restrict__ Wb) {
    int i = blockIdx.x * 256 + threadIdx.x;
    if (i < 147456) {
        int kk = i & 15, oc = (i >> 4) & 127, ks = i >> 11;
        int z4 = ks & 3, kq = ks >> 2;          // kq = (g*3+r)*3+s in [0,18)
        int g = kq / 9, tap = kq - 9 * g;       // tap = r*3+s
        int z = z4 * 16 + kk;
        // w_t (128,2,64,3,3): ((o*2+g)*64+kh)*9 + tap,  z=kh
        A_t[i] = __float2bfloat16(w_t[((oc * 2 + g) * 64 + z) * 9 + tap]);
        // w_c (128,2,3,3,64): ((o*2+g)*9+tap)*64 + kd,  z=kd
        A_c[i] = __float2bfloat16(w_c[((oc * 2 + g) * 9 + tap) * 64 + z]);
    }
    if (i < 8192) {
        Wb[i] = __float2bfloat16(w_map[i]);   // w_map is (C,2C) row-major = [c][k]
    }
}

__device__ inline void pack_row_bf16(__hip_bfloat16* dst, const float* src) {
    unsigned short u[16];
#pragma unroll
    for (int j = 0; j < 16; ++j) u[j] = bfu(src[j]);
    uint4* q = reinterpret_cast<uint4*>(dst);
    q[0] = *reinterpret_cast<const uint4*>(&u[0]);
    q[1] = *reinterpret_cast<const uint4*>(&u[8]);
}

// ---------------- transpose x (B,N,C) -> Xc bf16, z4-plane layout [cg][z4][h*w][16] ------------
// v2: block covers 4 hw positions (256 flat n) x 64 c. bf16 LDS tile [n 256][c 68pad].
// Write phase: thread (c = t>>2, hwl = t&3): 4-lane groups emit 4x32B = 128B-contiguous
// runs per (c,z4) -> fixes the R5 regression (isolated 32B writes, ~4x write amp).
__global__ void k_trans_c(const float* __restrict__ x, __hip_bfloat16* __restrict__ Xc) {
    __shared__ unsigned short tile[256][68];
    int b = blockIdx.y;
    long n0 = (long)blockIdx.x * 256;
    int t = threadIdx.x;
    const float4* xp4 = (const float4*)(x + ((long)b * HWD + n0) * 64);
#pragma unroll
    for (int i = 0; i < 16; ++i) {
        int f4i = i * 256 + t;
        float4 v = xp4[f4i];
        int nl = f4i >> 4, c4 = (f4i & 15) * 4;
        ushort4 u;
        u.x = bfu(v.x); u.y = bfu(v.y); u.z = bfu(v.z); u.w = bfu(v.w);
        *(ushort4*)&tile[nl][c4] = u;
    }
    __syncthreads();
    int c = t >> 2, hwl = t & 3;
    int hw0 = blockIdx.x * 4;
    __hip_bfloat16* dst0 = Xc + (long)(b * 64 + c) * HWD + (long)(hw0 + hwl) * 16;
#pragma unroll
    for (int z4 = 0; z4 < 4; ++z4) {
        unsigned short u[16];
#pragma unroll
        for (int j = 0; j < 16; ++j) u[j] = tile[hwl * 64 + z4 * 16 + j][c];
        __hip_bfloat16* dst = dst0 + z4 * 65536;
        *(uint4*)dst = *(const uint4*)&u[0];
        *(uint4*)(dst + 8) = *(const uint4*)&u[8];
    }
}

// ---------------- transpose x -> Xt bf16, z4-plane layout [cg][z4][w*d][16] (inner 16 = h) -----
__global__ void k_trans_t(const float* __restrict__ x, __hip_bfloat16* __restrict__ Xt) {
    __shared__ unsigned short tile[256][68];   // [wdl*64+h][c]
    int b = blockIdx.y;
    int wd0 = blockIdx.x * 4;
    int t = threadIdx.x;
    const float* xb = x + (long)b * HWD * 64 + (long)wd0 * 64;
#pragma unroll
    for (int i = 0; i < 16; ++i) {
        int idx = i * 256 + t;              // float4 id over 64 h x 64 f
        int h = idx >> 6, f = idx & 63;     // per h: 4 wd x 64 c = 1KB contiguous
        float4 v = *(const float4*)(xb + (long)h * 262144 + f * 4);
        int wdl = f >> 4, c4 = (f & 15) * 4;
        ushort4 u;
        u.x = bfu(v.x); u.y = bfu(v.y); u.z = bfu(v.z); u.w = bfu(v.w);
        *(ushort4*)&tile[wdl * 64 + h][c4] = u;
    }
    __syncthreads();
    int c = t >> 2, wdl = t & 3;
    __hip_bfloat16* dst0 = Xt + (long)(b * 64 + c) * HWD + (long)(wd0 + wdl) * 16;
#pragma unroll
    for (int z4 = 0; z4 < 4; ++z4) {
        unsigned short u[16];
#pragma unroll
        for (int j = 0; j < 16; ++j) u[j] = tile[wdl * 64 + z4 * 16 + j][c];
        __hip_bfloat16* dst = dst0 + z4 * 65536;
        *(uint4*)dst = *(const uint4*)&u[0];
        *(uint4*)(dst + 8) = *(const uint4*)&u[8];
    }
}

// ---------------- unified MFMA conv v3: NO LDS, NO barriers ----------------
// Per (b,ch) GEMM C[128][4096] = A[128][1152] * B, B from implicit im2col.
// With the z4-plane X layout, every MFMA fragment (A and B) is a single fully-contiguous
// 1KB wave load from L1/L2: lane(n=lane&31, kh=lane>>5) -> addr (pp*64+qq)*32B + kh*16B,
// qq lane-consecutive. So the K-loop is just 4 coalesced loads + 4 MFMAs per K-step,
// compiler-pipelined via counted vmcnt (no barrier drain), latency hidden by 4 blocks/CU.
// XCD swizzle: all 32 pt-blocks of one grp on one XCD (X window L1/L2-resident).
__global__ __launch_bounds__(256, 4) void k_conv_mfma(
        const __hip_bfloat16* __restrict__ X, const __hip_bfloat16* __restrict__ Aglob,
        const float* __restrict__ bias, float* __restrict__ Out) {
    int L = blockIdx.x;                       // 2048 = 64 grp * 32 pt
    int grp = (L & 7) * 8 + ((L >> 3) >> 5);  // XCD r handles grps [r*8, r*8+8)
    int pt = (L >> 3) & 31;
    int b = grp >> 5, ch = grp & 31;
    int p0 = pt * 2;
    const short* Xg = (const short*)(X + ((long)(b * 64 + 2 * ch)) * HWD);
    const short* Ag = (const short*)Aglob;
    int t = threadIdx.x;
    int lane = t & 63, wv = t >> 6;
    int O0 = (wv >> 1) * 64;              // wave oc base
    int N0 = (wv & 1) * 64;               // wave n base
    int lrow = lane & 31, lq = lane >> 5;
    int pr = N0 >> 6;                     // p-row within the 2-row tile (0 or 1)

    f32x16 acc00 = {0}, acc01 = {0}, acc10 = {0}, acc11 = {0};

    const short* Ap = Ag + (O0 + lrow) * 16 + lq * 8;   // + ks*2048 per step
    const uint4 zero4 = {0u, 0u, 0u, 0u};

    for (int kq = 0; kq < 18; ++kq) {
        int g = (kq >= 9) ? 1 : 0;
        int tap = kq - 9 * g;
        int r = tap / 3, s = tap - 3 * r;
        int pp = p0 + pr + r - 1;
        bool pok = (unsigned)pp < 64u;
        int qq0 = lrow + s - 1;
        int qq1 = qq0 + 32;
        bool q0ok = (unsigned)qq0 < 64u;
        bool q1ok = (unsigned)qq1 < 64u;
        const short* xb = Xg + (long)g * HWD + pp * 1024 + lq * 8;
#pragma unroll
        for (int z4 = 0; z4 < 4; ++z4) {
            int ks = kq * 4 + z4;
            uint4 b0u = zero4, b1u = zero4;
            if (pok) {
                const short* xz = xb + z4 * 65536;
                if (q0ok) b0u = *(const uint4*)(xz + qq0 * 16);
                if (q1ok) b1u = *(const uint4*)(xz + qq1 * 16);
            }
            uint4 a0u = *(const uint4*)(Ap + ks * 2048);
            uint4 a1u = *(const uint4*)(Ap + ks * 2048 + 512);
            bf16x8 a0 = *(bf16x8*)&a0u;
            bf16x8 a1 = *(bf16x8*)&a1u;
            bf16x8 b0 = *(bf16x8*)&b0u;
            bf16x8 b1 = *(bf16x8*)&b1u;
            acc00 = __builtin_amdgcn_mfma_f32_32x32x16_bf16(a0, b0, acc00, 0, 0, 0);
            acc01 = __builtin_amdgcn_mfma_f32_32x32x16_bf16(a0, b1, acc01, 0, 0, 0);
            acc10 = __builtin_amdgcn_mfma_f32_32x32x16_bf16(a1, b0, acc10, 0, 0, 0);
            acc11 = __builtin_amdgcn_mfma_f32_32x32x16_bf16(a1, b1, acc11, 0, 0, 0);
        }
    }

    // store: C/D layout col=lane&31, row=(reg&3)+8*(reg>>2)+4*(lane>>5)
    long base0 = ((long)(b * 64 + 2 * ch)) * HWD + (long)p0 * 64;
    int n0l = N0 + lrow, n1l = N0 + 32 + lrow;
    long noff0 = (long)(n0l >> 6) * 64 + (n0l & 63);
    long noff1 = (long)(n1l >> 6) * 64 + (n1l & 63);
#pragma unroll
    for (int reg = 0; reg < 16; ++reg) {
        int row = (reg & 3) + 8 * (reg >> 2) + 4 * lq;
        int oc0 = O0 + row, oc1 = O0 + 32 + row;
        long cb0 = base0 + (long)(oc0 >> 6) * HWD + (long)(oc0 & 63) * 4096;
        long cb1 = base0 + (long)(oc1 >> 6) * HWD + (long)(oc1 & 63) * 4096;
        float bs0 = bias[oc0], bs1 = bias[oc1];
        Out[cb0 + noff0] = acc00[reg] + bs0;
        Out[cb0 + noff1] = acc01[reg] + bs0;
        Out[cb1 + noff0] = acc10[reg] + bs1;
        Out[cb1 + noff1] = acc11[reg] + bs1;
    }
}

// ---------------- attn: At[b,c,h,w2,d] = sum_w Cc[b,c,w2,h,w] * T[b,c,w2,w,d] (bf16 out) ----
__global__ void k_attn(const float* __restrict__ Cc, const float* __restrict__ T,
                       __hip_bfloat16* __restrict__ At) {
    __shared__ float As[64][65];
    __shared__ float Bs[64][64];
    int bc = blockIdx.x >> 6, w2 = blockIdx.x & 63;
    const float* Ap = Cc + ((long)bc * 64 + w2) * 4096;
    const float* Bp = T + ((long)bc * 64 + w2) * 4096;
    int t = threadIdx.x;
#pragma unroll
    for (int e0 = 0; e0 < 4096; e0 += 256) {
        int e = e0 + t;
        int r = e >> 6, q = e & 63;
        As[r][q] = Ap[e];
        Bs[r][q] = Bp[e];
    }
    __syncthreads();
    int h = t >> 2, dg = (t & 3) * 16;
    f32x16 acc = {0};
    for (int k = 0; k < 64; ++k) {
        float a = As[h][k];
#pragma unroll
        for (int i = 0; i < 16; ++i)
            acc[i] = fmaf(a, Bs[k][dg + i], acc[i]);
    }
    float tmp[16];
#pragma unroll
    for (int i = 0; i < 16; ++i) tmp[i] = acc[i];
    pack_row_bf16(At + (long)bc * HWD + (long)h * 4096 + w2 * 64 + dg, tmp);
}

// ---------------- f: F[b,c,h,w,d] = sum_w2 Cc[b,c,w2,h,w] * T[b,c,w2,w,d] (bf16 out) ----
// block = (bc, 8-wide w-tile), 512 threads; A staged with float4 (32B contiguous),
// B coalesced; Bs rows padded to 68. XCD swizzle keeps one bc on one XCD.
__global__ __launch_bounds__(512, 4) void k_f(const float* __restrict__ Cc,
        const float* __restrict__ T, __hip_bfloat16* __restrict__ F) {
    __shared__ float As[16][64][8];   // [kk][h][w]        32 KB
    __shared__ float Bs[16][8][68];   // [kk][w][d(+pad)]  34 KB
    int L = blockIdx.x;               // 1024 = 128 bc * 8 wt
    int xcd = L & 7, j = L >> 3;      // j 0..127
    int bc = xcd * 16 + (j >> 3), wt = j & 7;
    const float* Ab = Cc + (long)bc * HWD + wt * 8;
    const float* Bb = T + (long)bc * HWD + wt * 8 * 64;
    int t = threadIdx.x;
    int w = t & 7, h = t >> 3;
    f32x16 acc0 = {0}, acc1 = {0}, acc2 = {0}, acc3 = {0};

    for (int w2c = 0; w2c < 4; ++w2c) {
        __syncthreads();
        // A stage: 16 kk x 64 h x 2 half-float4 (32B contiguous per (kk,h))
#pragma unroll
        for (int i = 0; i < 4; ++i) {
            int f = i * 512 + t;                       // 0..2047
            int half = f & 1, hh = (f >> 1) & 63, kk = f >> 7;
            float4 v = *(const float4*)(Ab + (long)(w2c * 16 + kk) * 4096 + hh * 64 + half * 4);
            *(float4*)&As[kk][hh][half * 4] = v;
        }
        // B stage: 16 kk x 8 w x 16 float4 (256B contiguous per (kk,w))
#pragma unroll
        for (int i = 0; i < 4; ++i) {
            int f = i * 512 + t;
            int d4 = f & 15, ww = (f >> 4) & 7, kk = f >> 7;
            float4 v = *(const float4*)(Bb + (long)(w2c * 16 + kk) * 4096 + ww * 64 + d4 * 4);
            *(float4*)&Bs[kk][ww][d4 * 4] = v;
        }
        __syncthreads();
        for (int kk = 0; kk < 16; ++kk) {
            float a = As[kk][h][w];
            const float* br = &Bs[kk][w][0];
#pragma unroll
            for (int i = 0; i < 16; ++i) {
                acc0[i] = fmaf(a, br[i], acc0[i]);
                acc1[i] = fmaf(a, br[16 + i], acc1[i]);
                acc2[i] = fmaf(a, br[32 + i], acc2[i]);
                acc3[i] = fmaf(a, br[48 + i], acc3[i]);
            }
        }
    }
    // store: F[bc][h][wt*8+w][d], 128B per thread (contiguous)
    __hip_bfloat16* Fp = F + (long)bc * HWD + (long)h * 4096 + (wt * 8 + w) * 64;
    float tmp[16];
#pragma unroll
    for (int i = 0; i < 16; ++i) tmp[i] = acc0[i];
    pack_row_bf16(Fp, tmp);
#pragma unroll
    for (int i = 0; i < 16; ++i) tmp[i] = acc1[i];
    pack_row_bf16(Fp + 16, tmp);
#pragma unroll
    for (int i = 0; i < 16; ++i) tmp[i] = acc2[i];
    pack_row_bf16(Fp + 32, tmp);
#pragma unroll
    for (int i = 0; i < 16; ++i) tmp[i] = acc3[i];
    pack_row_bf16(Fp + 48, tmp);
}

// ---------------- map v4 (MFMA): out[n][c] = gelu( sum_k P[n][k] Wb[k][c] + b_map[c] ) ----
// P[n][k<64] = bf16(x[n][k] * F[k][n]),  P[n][k>=64] = At[k-64][n].
__global__ __launch_bounds__(256, 4) void k_map(const float* __restrict__ x,
        const __hip_bfloat16* __restrict__ F, const __hip_bfloat16* __restrict__ At,
        const __hip_bfloat16* __restrict__ Wb, const float* __restrict__ b_map,
        float* __restrict__ out) {
    __shared__ float xs[16][257];             // 16448 B
    __shared__ __hip_bfloat16 fa[16][264];    //  8448 B, F or At chunk
    __shared__ short Pl[256][24];             // 12288 B, 16 k bf16 + 8 pad
    __shared__ short Wt[64][136];             // 17408 B, [c][k 128 + 8 pad]

    int t = threadIdx.x;
    long n0 = (long)blockIdx.x * 256;
    int b = (int)(n0 >> 18);
    long nn0 = n0 & (HWD - 1);
    const float* xblk = x + n0 * 64;
    const __hip_bfloat16* Fb = F + (long)b * 64 * HWD + nn0;
    const __hip_bfloat16* Ab = At + (long)b * 64 * HWD + nn0;

    // load W tile once: Wb[c][k] 64x128 bf16
#pragma unroll
    for (int i = 0; i < 4; ++i) {
        int e = i * 256 + t;                  // uint4 index, 1024 total
        int c = e >> 4, kk = (e & 15) * 8;
        *(uint4*)&Wt[c][kk] = *(const uint4*)((const short*)Wb + c * 128 + kk);
    }

    int lane = t & 63, wv = t >> 6;
    int lrow = lane & 31, lhalf = lane >> 5;
    f32x16 acc00 = {0}, acc01 = {0}, acc10 = {0}, acc11 = {0};

    for (int kc = 0; kc < 8; ++kc) {
        __syncthreads();   // prev chunk's Pl/xs/fa readers done; covers Wt load at kc=0
        if (kc < 4) {
            // stage x chunk: each 64B line fetched by one float4 instruction
#pragma unroll
            for (int i2 = 0; i2 < 4; ++i2) {
                int f = i2 * 256 + t;
                int nr = f >> 2, j4 = (f & 3) * 4;
                float4 v = *(const float4*)(xblk + nr * 64 + kc * 16 + j4);
                xs[j4 + 0][nr] = v.x;
                xs[j4 + 1][nr] = v.y;
                xs[j4 + 2][nr] = v.z;
                xs[j4 + 3][nr] = v.w;
            }
            // stage F chunk: 16 ch x 512B, uint4, fully coalesced
#pragma unroll
            for (int it = 0; it < 2; ++it) {
                int idx = it * 256 + t;
                int row = idx >> 5, seg = idx & 31;
                *(uint4*)&fa[row][seg * 8] =
                    *(const uint4*)(Fb + (long)(kc * 16 + row) * HWD + seg * 8);
            }
        } else {
            // stage At chunk
#pragma unroll
            for (int it = 0; it < 2; ++it) {
                int idx = it * 256 + t;
                int row = idx >> 5, seg = idx & 31;
                *(uint4*)&fa[row][seg * 8] =
                    *(const uint4*)(Ab + (long)((kc - 4) * 16 + row) * HWD + seg * 8);
            }
        }
        __syncthreads();
        // build P row t (16 bf16), write as 2x16B
        unsigned short pv[16];
        if (kc < 4) {
#pragma unroll
            for (int k2 = 0; k2 < 16; ++k2) {
                float p = xs[k2][t] * __bfloat162float(fa[k2][t]);
                pv[k2] = bfu(p);
            }
        } else {
#pragma unroll
            for (int k2 = 0; k2 < 16; ++k2)
                pv[k2] = *reinterpret_cast<const unsigned short*>(&fa[k2][t]);
        }
        *(uint4*)&Pl[t][0] = *(uint4*)&pv[0];
        *(uint4*)&Pl[t][8] = *(uint4*)&pv[8];
        __syncthreads();
        // MFMA K-step: A = P rows (n), B = Wt rows (c)
        bf16x8 a0 = *(const bf16x8*)&Pl[wv * 64 + lrow][lhalf * 8];
        bf16x8 a1 = *(const bf16x8*)&Pl[wv * 64 + 32 + lrow][lhalf * 8];
        bf16x8 b0 = *(const bf16x8*)&Wt[lrow][kc * 16 + lhalf * 8];
        bf16x8 b1 = *(const bf16x8*)&Wt[32 + lrow][kc * 16 + lhalf * 8];
        acc00 = __builtin_amdgcn_mfma_f32_32x32x16_bf16(a0, b0, acc00, 0, 0, 0);
        acc01 = __builtin_amdgcn_mfma_f32_32x32x16_bf16(a0, b1, acc01, 0, 0, 0);
        acc10 = __builtin_amdgcn_mfma_f32_32x32x16_bf16(a1, b0, acc10, 0, 0, 0);
        acc11 = __builtin_amdgcn_mfma_f32_32x32x16_bf16(a1, b1, acc11, 0, 0, 0);
    }

    // epilogue: bias + exact GELU + store.
    // D layout: col(c) = lane&31, row(n) = (reg&3)+8*(reg>>2)+4*lhalf
    float bs0 = b_map[lrow];
    float bs1 = b_map[32 + lrow];
    const float inv_sqrt2 = 0.70710678118654752440f;
    float* ob = out + (n0 + wv * 64) * 64;
#pragma unroll
    for (int reg = 0; reg < 16; ++reg) {
        int nrow = (reg & 3) + 8 * (reg >> 2) + 4 * lhalf;
        float v00 = acc00[reg] + bs0;
        float v01 = acc01[reg] + bs1;
        float v10 = acc10[reg] + bs0;
        float v11 = acc11[reg] + bs1;
        v00 = 0.5f * v00 * (1.f + erff(v00 * inv_sqrt2));
        v01 = 0.5f * v01 * (1.f + erff(v01 * inv_sqrt2));
        v10 = 0.5f * v10 * (1.f + erff(v10 * inv_sqrt2));
        v11 = 0.5f * v11 * (1.f + erff(v11 * inv_sqrt2));
        ob[(long)nrow * 64 + lrow] = v00;            // lanes 0-31 + 32-63: 2x128B contig
        ob[(long)nrow * 64 + 32 + lrow] = v01;
        ob[(long)(32 + nrow) * 64 + lrow] = v10;
        ob[(long)(32 + nrow) * 64 + 32 + lrow] = v11;
    }
}

extern "C" void kernel_launch(void* const* d_in, const int* in_sizes, int n_in,
                              void* d_out, int out_size, void* d_ws, size_t ws_size,
                              hipStream_t stream) {
    const float* x     = (const float*)d_in[0];
    const float* w_t   = (const float*)d_in[1];
    const float* b_t   = (const float*)d_in[2];
    const float* w_c   = (const float*)d_in[3];
    const float* b_c   = (const float*)d_in[4];
    const float* w_map = (const float*)d_in[5];
    const float* b_map = (const float*)d_in[6];
    float* out = (float*)d_out;
    float* ws = (float*)d_ws;

    // ws layout (float offsets), ~269 MB total:
    //  [0,        16777216)  Xc bf16  (33.5M elem)  -> reused as At bf16 after conv_c
    //  [16777216, 33554432)  Xt bf16                -> reused as F bf16 after conv_t
    //  [33554432, 67108864)  T fp32
    //  [67108864, ...)       A_t bf16 (147456) | A_c bf16 (147456) | Wb bf16 (8192)
    __hip_bfloat16* Xc = (__hip_bfloat16*)ws;
    __hip_bfloat16* Xt = (__hip_bfloat16*)(ws + 16777216L);
    float* T = ws + 33554432L;
    float* Cc = out;                                     // d_out as scratch
    __hip_bfloat16* A_t = (__hip_bfloat16*)(ws + 67108864L);
    __hip_bfloat16* A_c = (__hip_bfloat16*)(ws + 67182592L);
    __hip_bfloat16* Wb = (__hip_bfloat16*)(ws + 67256320L);
    __hip_bfloat16* At_bf = Xc;                          // 67 MB, Xc dead after convs
    __hip_bfloat16* F_bf = Xt;                           // 67 MB, Xt dead after convs

    hipLaunchKernelGGL(k_prep, dim3(576), dim3(256), 0, stream, w_t, w_c, w_map, A_t, A_c, Wb);
    hipLaunchKernelGGL(k_trans_c, dim3(1024, 2), dim3(256), 0, stream, x, Xc);
    hipLaunchKernelGGL(k_trans_t, dim3(1024, 2), dim3(256), 0, stream, x, Xt);
    hipLaunchKernelGGL(k_conv_mfma, dim3(2048), dim3(256), 0, stream, Xt, A_t, b_t, T);
    hipLaunchKernelGGL(k_conv_mfma, dim3(2048), dim3(256), 0, stream, Xc, A_c, b_c, Cc);
    hipLaunchKernelGGL(k_attn, dim3(8192), dim3(256), 0, stream, Cc, T, At_bf);
    hipLaunchKernelGGL(k_f, dim3(1024), dim3(512), 0, stream, Cc, T, F_bf);
    hipLaunchKernelGGL(k_map, dim3(2048), dim3(256), 0, stream, x, F_bf, At_bf, Wb, b_map, out);
}

// Round 7
// 802.086 us; speedup vs baseline: 1.0875x; 1.0250x over previous
//
#include <hip/hip_runtime.h>
#include <hip/hip_bf16.h>
#include <math.h>

#define HWD 262144   // 64*64*64

typedef __attribute__((ext_vector_type(8))) short bf16x8;   // 8 bf16 (4 VGPRs)
typedef __attribute__((ext_vector_type(16))) float f32x16;  // MFMA 32x32 accumulator

__device__ inline unsigned short bfu(float f) {
    __hip_bfloat16 h = __float2bfloat16(f);
    return *reinterpret_cast<unsigned short*>(&h);
}

// ---------------- prep: weights -> bf16 GEMM layout A[ks 72][oc 128][kk 16]; w_map -> Wb bf16 ----
// K order: k = ((g*3+r)*3+s)*64 + z,  ks=k>>4, kk=k&15.
__global__ void k_prep(const float* __restrict__ w_t, const float* __restrict__ w_c,
                       const float* __restrict__ w_map,
                       __hip_bfloat16* __restrict__ A_t, __hip_bfloat16* __restrict__ A_c,
                       __hip_bfloat16* __restrict__ Wb) {
    int i = blockIdx.x * 256 + threadIdx.x;
    if (i < 147456) {
        int kk = i & 15, oc = (i >> 4) & 127, ks = i >> 11;
        int z4 = ks & 3, kq = ks >> 2;          // kq = (g*3+r)*3+s in [0,18)
        int g = kq / 9, tap = kq - 9 * g;       // tap = r*3+s
        int z = z4 * 16 + kk;
        // w_t (128,2,64,3,3): ((o*2+g)*64+kh)*9 + tap,  z=kh
        A_t[i] = __float2bfloat16(w_t[((oc * 2 + g) * 64 + z) * 9 + tap]);
        // w_c (128,2,3,3,64): ((o*2+g)*9+tap)*64 + kd,  z=kd
        A_c[i] = __float2bfloat16(w_c[((oc * 2 + g) * 9 + tap) * 64 + z]);
    }
    if (i < 8192) {
        Wb[i] = __float2bfloat16(w_map[i]);   // w_map is (C,2C) row-major = [c][k]
    }
}

__device__ inline void pack_row_bf16(__hip_bfloat16* dst, const float* src) {
    unsigned short u[16];
#pragma unroll
    for (int j = 0; j < 16; ++j) u[j] = bfu(src[j]);
    uint4* q = reinterpret_cast<uint4*>(dst);
    q[0] = *reinterpret_cast<const uint4*>(&u[0]);
    q[1] = *reinterpret_cast<const uint4*>(&u[8]);
}

// ---------------- transpose x (B,N,C) -> Xc bf16, z4-plane layout [cg][z4][h*w][16] ------------
__global__ void k_trans_c(const float* __restrict__ x, __hip_bfloat16* __restrict__ Xc) {
    __shared__ unsigned short tile[256][68];
    int b = blockIdx.y;
    long n0 = (long)blockIdx.x * 256;
    int t = threadIdx.x;
    const float4* xp4 = (const float4*)(x + ((long)b * HWD + n0) * 64);
#pragma unroll
    for (int i = 0; i < 16; ++i) {
        int f4i = i * 256 + t;
        float4 v = xp4[f4i];
        int nl = f4i >> 4, c4 = (f4i & 15) * 4;
        ushort4 u;
        u.x = bfu(v.x); u.y = bfu(v.y); u.z = bfu(v.z); u.w = bfu(v.w);
        *(ushort4*)&tile[nl][c4] = u;
    }
    __syncthreads();
    int c = t >> 2, hwl = t & 3;
    int hw0 = blockIdx.x * 4;
    __hip_bfloat16* dst0 = Xc + (long)(b * 64 + c) * HWD + (long)(hw0 + hwl) * 16;
#pragma unroll
    for (int z4 = 0; z4 < 4; ++z4) {
        unsigned short u[16];
#pragma unroll
        for (int j = 0; j < 16; ++j) u[j] = tile[hwl * 64 + z4 * 16 + j][c];
        __hip_bfloat16* dst = dst0 + z4 * 65536;
        *(uint4*)dst = *(const uint4*)&u[0];
        *(uint4*)(dst + 8) = *(const uint4*)&u[8];
    }
}

// ---------------- transpose x -> Xt bf16, z4-plane layout [cg][z4][w*d][16] (inner 16 = h) -----
__global__ void k_trans_t(const float* __restrict__ x, __hip_bfloat16* __restrict__ Xt) {
    __shared__ unsigned short tile[256][68];   // [wdl*64+h][c]
    int b = blockIdx.y;
    int wd0 = blockIdx.x * 4;
    int t = threadIdx.x;
    const float* xb = x + (long)b * HWD * 64 + (long)wd0 * 64;
#pragma unroll
    for (int i = 0; i < 16; ++i) {
        int idx = i * 256 + t;              // float4 id over 64 h x 64 f
        int h = idx >> 6, f = idx & 63;     // per h: 4 wd x 64 c = 1KB contiguous
        float4 v = *(const float4*)(xb + (long)h * 262144 + f * 4);
        int wdl = f >> 4, c4 = (f & 15) * 4;
        ushort4 u;
        u.x = bfu(v.x); u.y = bfu(v.y); u.z = bfu(v.z); u.w = bfu(v.w);
        *(ushort4*)&tile[wdl * 64 + h][c4] = u;
    }
    __syncthreads();
    int c = t >> 2, wdl = t & 3;
    __hip_bfloat16* dst0 = Xt + (long)(b * 64 + c) * HWD + (long)(wd0 + wdl) * 16;
#pragma unroll
    for (int z4 = 0; z4 < 4; ++z4) {
        unsigned short u[16];
#pragma unroll
        for (int j = 0; j < 16; ++j) u[j] = tile[wdl * 64 + z4 * 16 + j][c];
        __hip_bfloat16* dst = dst0 + z4 * 65536;
        *(uint4*)dst = *(const uint4*)&u[0];
        *(uint4*)(dst + 8) = *(const uint4*)&u[8];
    }
}

// ---------------- unified MFMA conv v4: direct frags + explicit register double-buffer --------
// R6 diagnosis: __launch_bounds__(256,4) caps regs at 128/thread (64 VGPR + 64 AGPR acc) ->
// compiler cannot hold even one kq (16 uint4) of loads in flight -> every kq serializes on
// L2 latency (MfmaUtil pinned ~22%). v4: launch_bounds(256,2) = 256 regs; fully-unrolled kq
// loop (compile-time r,s,g); two named Frag sets; loads for kq+1 issued BEFORE the 16 MFMAs
// of kq (512 matrix-cycles of latency cover per cluster). ILP replaces the lost TLP.
struct Frag { uint4 a0[4], a1[4], b0[4], b1[4]; };

__global__ __launch_bounds__(256, 2) void k_conv_mfma(
        const __hip_bfloat16* __restrict__ X, const __hip_bfloat16* __restrict__ Aglob,
        const float* __restrict__ bias, float* __restrict__ Out) {
    int L = blockIdx.x;                       // 2048 = 64 grp * 32 pt
    int grp = (L & 7) * 8 + ((L >> 3) >> 5);  // XCD r handles grps [r*8, r*8+8)
    int pt = (L >> 3) & 31;
    int b = grp >> 5, ch = grp & 31;
    int p0 = pt * 2;
    const short* Xg = (const short*)(X + ((long)(b * 64 + 2 * ch)) * HWD);
    const short* Ag = (const short*)Aglob;
    int t = threadIdx.x;
    int lane = t & 63, wv = t >> 6;
    int O0 = (wv >> 1) * 64;              // wave oc base
    int N0 = (wv & 1) * 64;               // wave n base
    int lrow = lane & 31, lq = lane >> 5;
    int pr = N0 >> 6;                     // p-row within the 2-row tile (0 or 1)

    f32x16 acc00 = {0}, acc01 = {0}, acc10 = {0}, acc11 = {0};

    const short* Ap = Ag + (O0 + lrow) * 16 + lq * 8;   // + ks*2048 per step
    const short* XgL = Xg + lrow * 16 + lq * 8;         // per-lane invariant offset
    const uint4 zero4 = {0u, 0u, 0u, 0u};

    auto loadKq = [&](int kq, Frag& f) {
        int g = (kq >= 9) ? 1 : 0;
        int tap = kq - 9 * g;
        int r = tap / 3, s = tap - 3 * r;       // compile-time after full unroll
        int pp = p0 + pr + r - 1;
        bool pok = (unsigned)pp < 64u;
        bool q0ok = pok && ((s > 0) || (lrow != 0));
        bool q1ok = pok && ((s < 2) || (lrow != 31));
        const short* px = XgL + ((long)g * HWD + pp * 1024 + (s - 1) * 16);
#pragma unroll
        for (int z4 = 0; z4 < 4; ++z4) {
            int ks = kq * 4 + z4;
            f.b0[z4] = q0ok ? *(const uint4*)(px + z4 * 65536) : zero4;
            f.b1[z4] = q1ok ? *(const uint4*)(px + z4 * 65536 + 512) : zero4;
            f.a0[z4] = *(const uint4*)(Ap + ks * 2048);
            f.a1[z4] = *(const uint4*)(Ap + ks * 2048 + 512);
        }
    };
    auto mfmaKq = [&](Frag& f) {
#pragma unroll
        for (int z4 = 0; z4 < 4; ++z4) {
            bf16x8 a0 = *(bf16x8*)&f.a0[z4];
            bf16x8 a1 = *(bf16x8*)&f.a1[z4];
            bf16x8 b0 = *(bf16x8*)&f.b0[z4];
            bf16x8 b1 = *(bf16x8*)&f.b1[z4];
            acc00 = __builtin_amdgcn_mfma_f32_32x32x16_bf16(a0, b0, acc00, 0, 0, 0);
            acc01 = __builtin_amdgcn_mfma_f32_32x32x16_bf16(a0, b1, acc01, 0, 0, 0);
            acc10 = __builtin_amdgcn_mfma_f32_32x32x16_bf16(a1, b0, acc10, 0, 0, 0);
            acc11 = __builtin_amdgcn_mfma_f32_32x32x16_bf16(a1, b1, acc11, 0, 0, 0);
        }
    };

    Frag fA, fB;
    loadKq(0, fA);
#pragma unroll
    for (int k2 = 0; k2 < 9; ++k2) {
        loadKq(2 * k2 + 1, fB);     // in flight while fA's MFMAs run
        mfmaKq(fA);
        if (2 * k2 + 2 < 18) loadKq(2 * k2 + 2, fA);
        mfmaKq(fB);
    }

    // store: C/D layout col=lane&31, row=(reg&3)+8*(reg>>2)+4*(lane>>5)
    long base0 = ((long)(b * 64 + 2 * ch)) * HWD + (long)p0 * 64;
    int n0l = N0 + lrow, n1l = N0 + 32 + lrow;
    long noff0 = (long)(n0l >> 6) * 64 + (n0l & 63);
    long noff1 = (long)(n1l >> 6) * 64 + (n1l & 63);
#pragma unroll
    for (int reg = 0; reg < 16; ++reg) {
        int row = (reg & 3) + 8 * (reg >> 2) + 4 * lq;
        int oc0 = O0 + row, oc1 = O0 + 32 + row;
        long cb0 = base0 + (long)(oc0 >> 6) * HWD + (long)(oc0 & 63) * 4096;
        long cb1 = base0 + (long)(oc1 >> 6) * HWD + (long)(oc1 & 63) * 4096;
        float bs0 = bias[oc0], bs1 = bias[oc1];
        Out[cb0 + noff0] = acc00[reg] + bs0;
        Out[cb0 + noff1] = acc01[reg] + bs0;
        Out[cb1 + noff0] = acc10[reg] + bs1;
        Out[cb1 + noff1] = acc11[reg] + bs1;
    }
}

// ---------------- attn v2: At[b,c,h,w2,d] = sum_w Cc[b,c,w2,h,w] * T[b,c,w2,w,d] (bf16 out) ----
// 128 threads, thread owns 2 h x 16 d -> 72B LDS per 32 FMAs (2x compute density vs v1).
// Math order per accumulator identical to v1 (bit-identical numerics).
__global__ __launch_bounds__(128) void k_attn(const float* __restrict__ Cc,
        const float* __restrict__ T, __hip_bfloat16* __restrict__ At) {
    __shared__ float As[64][65];   // [h][w]
    __shared__ float Bs[64][64];   // [w][d]
    int bc = blockIdx.x >> 6, w2 = blockIdx.x & 63;
    const float4* Ap4 = (const float4*)(Cc + ((long)bc * 64 + w2) * 4096);
    const float4* Bp4 = (const float4*)(T + ((long)bc * 64 + w2) * 4096);
    int t = threadIdx.x;
#pragma unroll
    for (int i = 0; i < 8; ++i) {
        int f = i * 128 + t;               // float4 id, 1024 total
        int r = f >> 4, q4 = (f & 15) * 4;
        float4 v = Ap4[f];
        As[r][q4 + 0] = v.x; As[r][q4 + 1] = v.y; As[r][q4 + 2] = v.z; As[r][q4 + 3] = v.w;
        float4 w = Bp4[f];
        *(float4*)&Bs[r][q4] = w;
    }
    __syncthreads();
    int h2 = t >> 2, dg = (t & 3) * 16;
    f32x16 acc0 = {0}, acc1 = {0};
    for (int k = 0; k < 64; ++k) {
        float a0 = As[h2][k];
        float a1 = As[h2 + 32][k];
        const float* br = &Bs[k][dg];
#pragma unroll
        for (int i = 0; i < 16; ++i) {
            acc0[i] = fmaf(a0, br[i], acc0[i]);
            acc1[i] = fmaf(a1, br[i], acc1[i]);
        }
    }
    float tmp[16];
    __hip_bfloat16* Ab = At + (long)bc * HWD + (long)h2 * 4096 + w2 * 64 + dg;
#pragma unroll
    for (int i = 0; i < 16; ++i) tmp[i] = acc0[i];
    pack_row_bf16(Ab, tmp);
#pragma unroll
    for (int i = 0; i < 16; ++i) tmp[i] = acc1[i];
    pack_row_bf16(Ab + 32L * 4096, tmp);
}

// ---------------- f: F[b,c,h,w,d] = sum_w2 Cc[b,c,w2,h,w] * T[b,c,w2,w,d] (bf16 out) ----
__global__ __launch_bounds__(512, 4) void k_f(const float* __restrict__ Cc,
        const float* __restrict__ T, __hip_bfloat16* __restrict__ F) {
    __shared__ float As[16][64][8];   // [kk][h][w]        32 KB
    __shared__ float Bs[16][8][68];   // [kk][w][d(+pad)]  34 KB
    int L = blockIdx.x;               // 1024 = 128 bc * 8 wt
    int xcd = L & 7, j = L >> 3;      // j 0..127
    int bc = xcd * 16 + (j >> 3), wt = j & 7;
    const float* Ab = Cc + (long)bc * HWD + wt * 8;
    const float* Bb = T + (long)bc * HWD + wt * 8 * 64;
    int t = threadIdx.x;
    int w = t & 7, h = t >> 3;
    f32x16 acc0 = {0}, acc1 = {0}, acc2 = {0}, acc3 = {0};

    for (int w2c = 0; w2c < 4; ++w2c) {
        __syncthreads();
        // A stage: 16 kk x 64 h x 2 half-float4 (32B contiguous per (kk,h))
#pragma unroll
        for (int i = 0; i < 4; ++i) {
            int f = i * 512 + t;                       // 0..2047
            int half = f & 1, hh = (f >> 1) & 63, kk = f >> 7;
            float4 v = *(const float4*)(Ab + (long)(w2c * 16 + kk) * 4096 + hh * 64 + half * 4);
            *(float4*)&As[kk][hh][half * 4] = v;
        }
        // B stage: 16 kk x 8 w x 16 float4 (256B contiguous per (kk,w))
#pragma unroll
        for (int i = 0; i < 4; ++i) {
            int f = i * 512 + t;
            int d4 = f & 15, ww = (f >> 4) & 7, kk = f >> 7;
            float4 v = *(const float4*)(Bb + (long)(w2c * 16 + kk) * 4096 + ww * 64 + d4 * 4);
            *(float4*)&Bs[kk][ww][d4 * 4] = v;
        }
        __syncthreads();
        for (int kk = 0; kk < 16; ++kk) {
            float a = As[kk][h][w];
            const float* br = &Bs[kk][w][0];
#pragma unroll
            for (int i = 0; i < 16; ++i) {
                acc0[i] = fmaf(a, br[i], acc0[i]);
                acc1[i] = fmaf(a, br[16 + i], acc1[i]);
                acc2[i] = fmaf(a, br[32 + i], acc2[i]);
                acc3[i] = fmaf(a, br[48 + i], acc3[i]);
            }
        }
    }
    // store: F[bc][h][wt*8+w][d], 128B per thread (contiguous)
    __hip_bfloat16* Fp = F + (long)bc * HWD + (long)h * 4096 + (wt * 8 + w) * 64;
    float tmp[16];
#pragma unroll
    for (int i = 0; i < 16; ++i) tmp[i] = acc0[i];
    pack_row_bf16(Fp, tmp);
#pragma unroll
    for (int i = 0; i < 16; ++i) tmp[i] = acc1[i];
    pack_row_bf16(Fp + 16, tmp);
#pragma unroll
    for (int i = 0; i < 16; ++i) tmp[i] = acc2[i];
    pack_row_bf16(Fp + 32, tmp);
#pragma unroll
    for (int i = 0; i < 16; ++i) tmp[i] = acc3[i];
    pack_row_bf16(Fp + 48, tmp);
}

// ---------------- map v4 (MFMA): out[n][c] = gelu( sum_k P[n][k] Wb[k][c] + b_map[c] ) ----
// P[n][k<64] = bf16(x[n][k] * F[k][n]),  P[n][k>=64] = At[k-64][n].
__global__ __launch_bounds__(256, 4) void k_map(const float* __restrict__ x,
        const __hip_bfloat16* __restrict__ F, const __hip_bfloat16* __restrict__ At,
        const __hip_bfloat16* __restrict__ Wb, const float* __restrict__ b_map,
        float* __restrict__ out) {
    __shared__ float xs[16][257];             // 16448 B
    __shared__ __hip_bfloat16 fa[16][264];    //  8448 B, F or At chunk
    __shared__ short Pl[256][24];             // 12288 B, 16 k bf16 + 8 pad
    __shared__ short Wt[64][136];             // 17408 B, [c][k 128 + 8 pad]

    int t = threadIdx.x;
    long n0 = (long)blockIdx.x * 256;
    int b = (int)(n0 >> 18);
    long nn0 = n0 & (HWD - 1);
    const float* xblk = x + n0 * 64;
    const __hip_bfloat16* Fb = F + (long)b * 64 * HWD + nn0;
    const __hip_bfloat16* Ab = At + (long)b * 64 * HWD + nn0;

    // load W tile once: Wb[c][k] 64x128 bf16
#pragma unroll
    for (int i = 0; i < 4; ++i) {
        int e = i * 256 + t;                  // uint4 index, 1024 total
        int c = e >> 4, kk = (e & 15) * 8;
        *(uint4*)&Wt[c][kk] = *(const uint4*)((const short*)Wb + c * 128 + kk);
    }

    int lane = t & 63, wv = t >> 6;
    int lrow = lane & 31, lhalf = lane >> 5;
    f32x16 acc00 = {0}, acc01 = {0}, acc10 = {0}, acc11 = {0};

    for (int kc = 0; kc < 8; ++kc) {
        __syncthreads();   // prev chunk's Pl/xs/fa readers done; covers Wt load at kc=0
        if (kc < 4) {
            // stage x chunk: each 64B line fetched by one float4 instruction
#pragma unroll
            for (int i2 = 0; i2 < 4; ++i2) {
                int f = i2 * 256 + t;
                int nr = f >> 2, j4 = (f & 3) * 4;
                float4 v = *(const float4*)(xblk + nr * 64 + kc * 16 + j4);
                xs[j4 + 0][nr] = v.x;
                xs[j4 + 1][nr] = v.y;
                xs[j4 + 2][nr] = v.z;
                xs[j4 + 3][nr] = v.w;
            }
            // stage F chunk: 16 ch x 512B, uint4, fully coalesced
#pragma unroll
            for (int it = 0; it < 2; ++it) {
                int idx = it * 256 + t;
                int row = idx >> 5, seg = idx & 31;
                *(uint4*)&fa[row][seg * 8] =
                    *(const uint4*)(Fb + (long)(kc * 16 + row) * HWD + seg * 8);
            }
        } else {
            // stage At chunk
#pragma unroll
            for (int it = 0; it < 2; ++it) {
                int idx = it * 256 + t;
                int row = idx >> 5, seg = idx & 31;
                *(uint4*)&fa[row][seg * 8] =
                    *(const uint4*)(Ab + (long)((kc - 4) * 16 + row) * HWD + seg * 8);
            }
        }
        __syncthreads();
        // build P row t (16 bf16), write as 2x16B
        unsigned short pv[16];
        if (kc < 4) {
#pragma unroll
            for (int k2 = 0; k2 < 16; ++k2) {
                float p = xs[k2][t] * __bfloat162float(fa[k2][t]);
                pv[k2] = bfu(p);
            }
        } else {
#pragma unroll
            for (int k2 = 0; k2 < 16; ++k2)
                pv[k2] = *reinterpret_cast<const unsigned short*>(&fa[k2][t]);
        }
        *(uint4*)&Pl[t][0] = *(uint4*)&pv[0];
        *(uint4*)&Pl[t][8] = *(uint4*)&pv[8];
        __syncthreads();
        // MFMA K-step: A = P rows (n), B = Wt rows (c)
        bf16x8 a0 = *(const bf16x8*)&Pl[wv * 64 + lrow][lhalf * 8];
        bf16x8 a1 = *(const bf16x8*)&Pl[wv * 64 + 32 + lrow][lhalf * 8];
        bf16x8 b0 = *(const bf16x8*)&Wt[lrow][kc * 16 + lhalf * 8];
        bf16x8 b1 = *(const bf16x8*)&Wt[32 + lrow][kc * 16 + lhalf * 8];
        acc00 = __builtin_amdgcn_mfma_f32_32x32x16_bf16(a0, b0, acc00, 0, 0, 0);
        acc01 = __builtin_amdgcn_mfma_f32_32x32x16_bf16(a0, b1, acc01, 0, 0, 0);
        acc10 = __builtin_amdgcn_mfma_f32_32x32x16_bf16(a1, b0, acc10, 0, 0, 0);
        acc11 = __builtin_amdgcn_mfma_f32_32x32x16_bf16(a1, b1, acc11, 0, 0, 0);
    }

    // epilogue: bias + exact GELU + store.
    // D layout: col(c) = lane&31, row(n) = (reg&3)+8*(reg>>2)+4*lhalf
    float bs0 = b_map[lrow];
    float bs1 = b_map[32 + lrow];
    const float inv_sqrt2 = 0.70710678118654752440f;
    float* ob = out + (n0 + wv * 64) * 64;
#pragma unroll
    for (int reg = 0; reg < 16; ++reg) {
        int nrow = (reg & 3) + 8 * (reg >> 2) + 4 * lhalf;
        float v00 = acc00[reg] + bs0;
        float v01 = acc01[reg] + bs1;
        float v10 = acc10[reg] + bs0;
        float v11 = acc11[reg] + bs1;
        v00 = 0.5f * v00 * (1.f + erff(v00 * inv_sqrt2));
        v01 = 0.5f * v01 * (1.f + erff(v01 * inv_sqrt2));
        v10 = 0.5f * v10 * (1.f + erff(v10 * inv_sqrt2));
        v11 = 0.5f * v11 * (1.f + erff(v11 * inv_sqrt2));
        ob[(long)nrow * 64 + lrow] = v00;            // lanes 0-31 + 32-63: 2x128B contig
        ob[(long)nrow * 64 + 32 + lrow] = v01;
        ob[(long)(32 + nrow) * 64 + lrow] = v10;
        ob[(long)(32 + nrow) * 64 + 32 + lrow] = v11;
    }
}

extern "C" void kernel_launch(void* const* d_in, const int* in_sizes, int n_in,
                              void* d_out, int out_size, void* d_ws, size_t ws_size,
                              hipStream_t stream) {
    const float* x     = (const float*)d_in[0];
    const float* w_t   = (const float*)d_in[1];
    const float* b_t   = (const float*)d_in[2];
    const float* w_c   = (const float*)d_in[3];
    const float* b_c   = (const float*)d_in[4];
    const float* w_map = (const float*)d_in[5];
    const float* b_map = (const float*)d_in[6];
    float* out = (float*)d_out;
    float* ws = (float*)d_ws;

    // ws layout (float offsets), ~269 MB total:
    //  [0,        16777216)  Xc bf16  (33.5M elem)  -> reused as At bf16 after conv_c
    //  [16777216, 33554432)  Xt bf16                -> reused as F bf16 after conv_t
    //  [33554432, 67108864)  T fp32
    //  [67108864, ...)       A_t bf16 (147456) | A_c bf16 (147456) | Wb bf16 (8192)
    __hip_bfloat16* Xc = (__hip_bfloat16*)ws;
    __hip_bfloat16* Xt = (__hip_bfloat16*)(ws + 16777216L);
    float* T = ws + 33554432L;
    float* Cc = out;                                     // d_out as scratch
    __hip_bfloat16* A_t = (__hip_bfloat16*)(ws + 67108864L);
    __hip_bfloat16* A_c = (__hip_bfloat16*)(ws + 67182592L);
    __hip_bfloat16* Wb = (__hip_bfloat16*)(ws + 67256320L);
    __hip_bfloat16* At_bf = Xc;                          // 67 MB, Xc dead after convs
    __hip_bfloat16* F_bf = Xt;                           // 67 MB, Xt dead after convs

    hipLaunchKernelGGL(k_prep, dim3(576), dim3(256), 0, stream, w_t, w_c, w_map, A_t, A_c, Wb);
    hipLaunchKernelGGL(k_trans_c, dim3(1024, 2), dim3(256), 0, stream, x, Xc);
    hipLaunchKernelGGL(k_trans_t, dim3(1024, 2), dim3(256), 0, stream, x, Xt);
    hipLaunchKernelGGL(k_conv_mfma, dim3(2048), dim3(256), 0, stream, Xt, A_t, b_t, T);
    hipLaunchKernelGGL(k_conv_mfma, dim3(2048), dim3(256), 0, stream, Xc, A_c, b_c, Cc);
    hipLaunchKernelGGL(k_attn, dim3(8192), dim3(128), 0, stream, Cc, T, At_bf);
    hipLaunchKernelGGL(k_f, dim3(1024), dim3(512), 0, stream, Cc, T, F_bf);
    hipLaunchKernelGGL(k_map, dim3(2048), dim3(256), 0, stream, x, F_bf, At_bf, Wb, b_map, out);
}